// Round 9
// baseline (53.015 us; speedup 1.0000x reference)
//
#include <hip/hip_runtime.h>
#include <hip/hip_bf16.h>

// Problem constants
#define DM    1024          // d_model
#define NH    2             // heads
#define IDX   32            // idx dim per head
#define HQ    (NH*IDX)      // 64 query cols
#define TT    4096          // tokens per batch
#define BB    2             // batch
#define RR    (BB*TT)       // 8192 total rows
#define NC    112           // padded projection cols (64 Q + 32 K + 2 w + 14 pad)
#define NTIL  7             // NC/16
#define SCW   512           // score s-chunk width
#define SCH   (TT/SCW)      // 8 s-chunks per batch

typedef short  s16x4 __attribute__((ext_vector_type(4)));
typedef short  s16x8 __attribute__((ext_vector_type(8)));
typedef float  f32x4 __attribute__((ext_vector_type(4)));

// HW bf16 convert (compiler emits v_cvt_pk_bf16_f32 / RNE).
__device__ __forceinline__ unsigned short f2bf(float f) {
    __hip_bfloat16 h = __float2bfloat16(f);
    return __builtin_bit_cast(unsigned short, h);
}

// ---------------------------------------------------------------------------
// Kernel 1: pack Wq|Wk|Ww into transposed bf16 WcatT[NC][DM]
// ---------------------------------------------------------------------------
__global__ __launch_bounds__(256) void prep_wcat(const float* __restrict__ Wq,
                                                 const float* __restrict__ Wk,
                                                 const float* __restrict__ Ww,
                                                 unsigned short* __restrict__ WcatT) {
    int idx = blockIdx.x * 256 + threadIdx.x;        // NC*DM total
    int j = idx >> 10;                               // col  (0..111)
    int i = idx & 1023;                              // k    (0..1023)
    float v = 0.f;
    if (j < 64)       v = Wq[i * HQ + j];
    else if (j < 96)  v = Wk[i * IDX + (j - 64)];
    else if (j < 98)  v = Ww[i * NH + (j - 96)];
    WcatT[j * DM + i] = f2bf(v);
}

// ---------------------------------------------------------------------------
// Kernel 2: projections — H-stride fix. The x-read is decoupled from the
// MFMA lane layout via an LDS round-trip:
//   stage: 16 rows x 4KB fp32 read CONTIGUOUSLY (each wave instr = 1KB
//          burst; one row = 256 threads x float4), cvt to bf16, ds_write
//          into a [16][2048B] XOR-swizzled tile (byte ^= (row&7)<<4).
//   compute: wave = K-quarter; A-frags via ds_read_b128 (swizzle -> even
//          bank spread); W-frags from global (L2-resident); 56 MFMA/wave.
//   reduce: 4-way cross-wave sum via LDS (aliased onto stage buffer),
//          epilogue stores unchanged from prior rounds (attribution).
// ---------------------------------------------------------------------------
__global__ __launch_bounds__(256) void proj_kernel(const float* __restrict__ x,
                                                   const unsigned short* __restrict__ WcatT,
                                                   unsigned short* __restrict__ Qb,
                                                   unsigned short* __restrict__ Kb,
                                                   float* __restrict__ wb) {
    __shared__ __align__(16) unsigned char smem[32768];   // stage tile / red

    const int tid  = threadIdx.x;
    const int wave = tid >> 6;               // K-quarter 0..3
    const int lane = tid & 63;
    const int r0   = blockIdx.x * 16;
    const int lrow = lane & 15;
    const int lseg = lane >> 4;

    // ---- stage phase: contiguous x read -> swizzled bf16 LDS tile ----
    {
        const float4* xsrc = (const float4*)(x + (size_t)r0 * DM);
        #pragma unroll 8
        for (int i = 0; i < 16; ++i) {                 // i = row in tile
            float4 a = xsrc[i * 256 + tid];            // wave instr: 1KB burst
            const int boff = i * 2048 + ((tid * 8) ^ ((i & 7) << 4));
            s16x4 h;
            h[0] = (short)f2bf(a.x); h[1] = (short)f2bf(a.y);
            h[2] = (short)f2bf(a.z); h[3] = (short)f2bf(a.w);
            *(s16x4*)(smem + boff) = h;
        }
    }
    __syncthreads();

    // ---- compute phase: wave's K-quarter (256 cols), all 7 tiles ----
    f32x4 acc[NTIL] = {};
    const unsigned short* wr = WcatT + (size_t)lrow * DM + wave * 256 + lseg * 8;

    #pragma unroll
    for (int kc = 0; kc < 8; ++kc) {                   // 8 x K=32 steps
        const int boff = lrow * 2048 +
            ((wave * 512 + kc * 64 + lseg * 16) ^ ((lrow & 7) << 4));
        s16x8 af = *(const s16x8*)(smem + boff);
        #pragma unroll
        for (int t = 0; t < NTIL; ++t) {
            s16x8 bfv = *(const s16x8*)(wr + (size_t)t * 16 * DM + kc * 32);
            acc[t] = __builtin_amdgcn_mfma_f32_16x16x32_bf16(af, bfv, acc[t], 0, 0, 0);
        }
    }

    __syncthreads();                                   // done reading stage
    // ---- cross-wave reduce (red aliases stage buffer: 28672B <= 32KB) ----
    float* red = (float*)smem;                         // [4][NTIL][64][4]
    #pragma unroll
    for (int t = 0; t < NTIL; ++t)
        *(f32x4*)&red[(((wave * NTIL) + t) * 64 + lane) * 4] = acc[t];
    __syncthreads();

    #pragma unroll
    for (int u = 0; u < 2; ++u) {
        const int t = wave + u * 4;                    // tiles: w, w+4
        if (t >= NTIL) break;
        f32x4 s = *(const f32x4*)&red[((0 * NTIL + t) * 64 + lane) * 4];
        s += *(const f32x4*)&red[((1 * NTIL + t) * 64 + lane) * 4];
        s += *(const f32x4*)&red[((2 * NTIL + t) * 64 + lane) * 4];
        s += *(const f32x4*)&red[((3 * NTIL + t) * 64 + lane) * 4];
        const int col = t * 16 + lrow;
        #pragma unroll
        for (int r = 0; r < 4; ++r) {
            int row = r0 + lseg * 4 + r;
            float v = s[r];
            if (col < 64)       Qb[(size_t)row * HQ + col]         = f2bf(v);
            else if (col < 96)  Kb[(size_t)row * IDX + (col - 64)] = f2bf(v);
            else if (col < 98)  wb[(size_t)row * NH + (col - 96)]  = v;
        }
    }
}

// ---------------------------------------------------------------------------
// Kernel 3: scores (measured at the 6.1 TB/s write ceiling in R7 diag).
// Swapped mfma operands: D = K_frag * Q_frag -> lane holds 4 consecutive
// s-values of one t-row -> dwordx4 stores. Wave: 16 t-rows x 512 s-cols.
// ---------------------------------------------------------------------------
__global__ __launch_bounds__(256) void score_kernel(const unsigned short* __restrict__ Qb,
                                                    const unsigned short* __restrict__ Kb,
                                                    const float* __restrict__ wb,
                                                    float* __restrict__ out) {
    const int rb   = blockIdx.x >> 3;    // 0..127 row-block (64 rows)
    const int sc   = blockIdx.x & (SCH - 1);
    const int wave = threadIdx.x >> 6;
    const int lane = threadIdx.x & 63;
    const int trow = lane & 15;
    const int lseg = lane >> 4;

    const int t0 = rb * 64 + wave * 16;          // global row in [0,8192)
    const int b  = t0 >> 12;                     // batch

    const unsigned short* qrow = Qb + (size_t)(t0 + trow) * HQ + lseg * 8;
    s16x8 qb0 = *(const s16x8*)(qrow);           // head 0 fragment (B operand)
    s16x8 qb1 = *(const s16x8*)(qrow + IDX);     // head 1

    float2 wt = *(const float2*)(wb + (size_t)(t0 + trow) * NH);

    const int s0 = sc * SCW;
    const unsigned short* kbase =
        Kb + ((size_t)(b * TT) + s0 + trow) * IDX + lseg * 8;
    float* obase = out + (size_t)(t0 + trow) * TT + s0 + lseg * 4;

    const f32x4 zero = {0.f, 0.f, 0.f, 0.f};

    #pragma unroll 4
    for (int it = 0; it < SCW / 16; ++it) {
        s16x8 kb = *(const s16x8*)(kbase + (size_t)it * 16 * IDX);
        f32x4 d0 = __builtin_amdgcn_mfma_f32_16x16x32_bf16(kb, qb0, zero, 0, 0, 0);
        f32x4 d1 = __builtin_amdgcn_mfma_f32_16x16x32_bf16(kb, qb1, zero, 0, 0, 0);
        f32x4 v;
        #pragma unroll
        for (int r = 0; r < 4; ++r)
            v[r] = wt.x * fmaxf(d0[r], 0.f) + wt.y * fmaxf(d1[r], 0.f);
        *(f32x4*)(obase + it * 16) = v;
    }
}

// ---------------------------------------------------------------------------
extern "C" void kernel_launch(void* const* d_in, const int* in_sizes, int n_in,
                              void* d_out, int out_size, void* d_ws, size_t ws_size,
                              hipStream_t stream) {
    const float* x  = (const float*)d_in[0];
    const float* Wq = (const float*)d_in[1];
    const float* Wk = (const float*)d_in[2];
    const float* Ww = (const float*)d_in[3];
    float* out = (float*)d_out;

    // workspace layout (16B aligned)
    char* ws = (char*)d_ws;
    unsigned short* WcatT = (unsigned short*)ws;                    // NC*DM*2   = 229376
    unsigned short* Qb    = (unsigned short*)(ws + 256 * 1024);     // RR*HQ*2   = 1 MB
    unsigned short* Kb    = (unsigned short*)(ws + 256 * 1024 + 1024 * 1024);  // RR*IDX*2 = 512 KB
    float*          wb    = (float*)(ws + 256 * 1024 + 1024 * 1024 + 512 * 1024); // RR*NH*4 = 64 KB

    hipLaunchKernelGGL(prep_wcat, dim3((NC * DM) / 256), dim3(256), 0, stream,
                       Wq, Wk, Ww, WcatT);
    hipLaunchKernelGGL(proj_kernel, dim3(RR / 16), dim3(256), 0, stream,
                       x, WcatT, Qb, Kb, wb);
    hipLaunchKernelGGL(score_kernel, dim3((RR / 64) * SCH), dim3(256), 0, stream,
                       Qb, Kb, wb, out);
}